// Round 10
// baseline (199.569 us; speedup 1.0000x reference)
//
#include <hip/hip_runtime.h>

#define DEV __device__ __forceinline__

typedef __attribute__((ext_vector_type(8))) __bf16 bf16x8;
typedef __attribute__((ext_vector_type(4))) __bf16 bf16x4;
typedef __attribute__((ext_vector_type(4))) float f32x4;
typedef __attribute__((ext_vector_type(4))) float float4v;

typedef __attribute__((address_space(1))) const void ga_void;
typedef __attribute__((address_space(3))) void la_void;

constexpr float LOG2E = 1.44269504089f;
constexpr float ATT_SCALE2 = 0.125f * 1.44269504089f;  // 1/sqrt(64) * log2(e)

#if __has_builtin(__builtin_amdgcn_exp2f)
#define EXP2(x) __builtin_amdgcn_exp2f(x)
#else
#define EXP2(x) exp2f(x)
#endif

DEV void gload16(const void* g, void* l) {
  __builtin_amdgcn_global_load_lds((ga_void*)g, (la_void*)l, 16, 0, 0);
}

DEV f32x4 mfma_bf16(bf16x8 a, bf16x8 b, f32x4 c) {
  return __builtin_amdgcn_mfma_f32_16x16x32_bf16(a, b, c, 0, 0, 0);
}

// ---------------- cast x (f32 -> bf16), vectorized ----------------
__global__ __launch_bounds__(256) void cast_x_kernel(
    const float* __restrict__ in, __bf16* __restrict__ out, int n4) {
  int i = blockIdx.x * blockDim.x + threadIdx.x;
  int stride = gridDim.x * blockDim.x;
  for (; i < n4; i += stride) {
    float4v v = ((const float4v*)in)[i];
    bf16x4 o;
    o[0] = (__bf16)v[0]; o[1] = (__bf16)v[1];
    o[2] = (__bf16)v[2]; o[3] = (__bf16)v[3];
    ((bf16x4*)out)[i] = o;
  }
}

// ---- fused transpose+cast of BOTH weights: f32 [512][Nc] -> bf16 [Nc][512] ----
// blocks 0..47 -> w_qkv (Nc=1536); blocks 48..63 -> w_out (Nc=512)
__global__ __launch_bounds__(256) void transpose_both_kernel(
    const float* __restrict__ wqkv, const float* __restrict__ wout,
    __bf16* __restrict__ wqkvT, __bf16* __restrict__ woutT) {
  __shared__ float tile[32][33];
  const float* in;
  __bf16* out;
  int Nc, bx;
  if (blockIdx.x < 48) { in = wqkv; out = wqkvT; Nc = 1536; bx = blockIdx.x * 32; }
  else                 { in = wout; out = woutT; Nc = 512;  bx = (blockIdx.x - 48) * 32; }
  int by = blockIdx.y * 32;
  int tx = threadIdx.x, ty = threadIdx.y;
#pragma unroll
  for (int i = ty; i < 32; i += 8)
    tile[i][tx] = in[(size_t)(by + i) * Nc + bx + tx];
  __syncthreads();
#pragma unroll
  for (int i = ty; i < 32; i += 8)
    out[(size_t)(bx + i) * 512 + by + tx] = (__bf16)tile[tx][i];
}

// ---------------- GEMM1: xb[8192x512] @ wqkvT^T -> split Q/K/Vt ----------------
__global__ __launch_bounds__(256) void gemm_qkv_kernel(
    const __bf16* __restrict__ A, const __bf16* __restrict__ Bt,
    const float* __restrict__ bias,
    __bf16* __restrict__ Qo, __bf16* __restrict__ Ko, __bf16* __restrict__ Vto) {
  __shared__ __align__(16) __bf16 As[2][128 * 32];
  __shared__ __align__(16) __bf16 Bs[2][128 * 32];
  const int tid = threadIdx.x;
  const int lane = tid & 63;
  const int w = tid >> 6;
  const int lr = lane & 15, lg = lane >> 4;
  const int m0 = blockIdx.x * 128, n0 = blockIdx.y * 128;
  const int wr = w >> 1, wc = w & 1;

  f32x4 acc[4][4] = {};

  auto stage = [&](int buf, int kt) {
#pragma unroll
    for (int cc = 0; cc < 2; ++cc) {
      int c = w * 2 + cc;
      int row = c * 16 + (lane >> 2);
      int slot = (lane & 3) ^ ((row >> 1) & 3);
      gload16(A + (size_t)(m0 + row) * 512 + kt * 32 + slot * 8, &As[buf][c * 512]);
      gload16(Bt + (size_t)(n0 + row) * 512 + kt * 32 + slot * 8, &Bs[buf][c * 512]);
    }
  };

  stage(0, 0);
  __syncthreads();
  for (int kt = 0; kt < 16; ++kt) {
    int cur = kt & 1;
    if (kt < 15) stage(cur ^ 1, kt + 1);
    bf16x8 av[4], bv[4];
#pragma unroll
    for (int i = 0; i < 4; ++i) {
      int row = wr * 64 + i * 16 + lr;
      av[i] = *(const bf16x8*)&As[cur][row * 32 + ((lg ^ ((row >> 1) & 3)) * 8)];
    }
#pragma unroll
    for (int j = 0; j < 4; ++j) {
      int row = wc * 64 + j * 16 + lr;
      bv[j] = *(const bf16x8*)&Bs[cur][row * 32 + ((lg ^ ((row >> 1) & 3)) * 8)];
    }
#pragma unroll
    for (int i = 0; i < 4; ++i)
#pragma unroll
      for (int j = 0; j < 4; ++j)
        acc[i][j] = mfma_bf16(av[i], bv[j], acc[i][j]);
    __syncthreads();
  }

  const int sec = n0 >> 9;
#pragma unroll
  for (int j = 0; j < 4; ++j) {
    int n = n0 + wc * 64 + j * 16 + lr;
    float bsv = bias[n];
    int nn = n & 511;
    int h = nn >> 6, d = nn & 63;
#pragma unroll
    for (int i = 0; i < 4; ++i) {
#pragma unroll
      for (int r = 0; r < 4; ++r) {
        int m = m0 + wr * 64 + i * 16 + lg * 4 + r;
        int b = m >> 10, nr = m & 1023;
        float v = acc[i][j][r] + bsv;
        if (sec == 0)
          Qo[(((size_t)(b * 8 + h)) * 1024 + nr) * 64 + d] = (__bf16)v;
        else if (sec == 1)
          Ko[(((size_t)(b * 8 + h)) * 1024 + nr) * 64 + d] = (__bf16)v;
        else
          Vto[(((size_t)(b * 8 + h)) * 64 + d) * 1024 + nr] = (__bf16)v;
      }
    }
  }
}

// ------- GEMM2: ctx[8192x512] @ woutT^T + b_out -> f32 out; 64x64 tile -------
__global__ __launch_bounds__(256) void gemm_out_kernel(
    const __bf16* __restrict__ A, const __bf16* __restrict__ Bt,
    const float* __restrict__ bias, float* __restrict__ out) {
  __shared__ __align__(16) __bf16 As[2][64 * 32];
  __shared__ __align__(16) __bf16 Bs[2][64 * 32];
  const int tid = threadIdx.x;
  const int lane = tid & 63;
  const int w = tid >> 6;
  const int lr = lane & 15, lg = lane >> 4;
  const int m0 = blockIdx.x * 64, n0 = blockIdx.y * 64;

  f32x4 acc[4] = {};

  auto stage = [&](int buf, int kt) {
    int row = tid >> 2;
    int sg = (tid & 3) ^ ((row >> 1) & 3);  // pre-swizzled source slot
    gload16(A + (size_t)(m0 + row) * 512 + kt * 32 + sg * 8, &As[buf][tid * 8]);
    gload16(Bt + (size_t)(n0 + row) * 512 + kt * 32 + sg * 8, &Bs[buf][tid * 8]);
  };

  stage(0, 0);
  __syncthreads();
  for (int kt = 0; kt < 16; ++kt) {
    int cur = kt & 1;
    if (kt < 15) stage(cur ^ 1, kt + 1);
    int arow = w * 16 + lr;
    bf16x8 av = *(const bf16x8*)&As[cur][arow * 32 + ((lg ^ ((arow >> 1) & 3)) * 8)];
#pragma unroll
    for (int j = 0; j < 4; ++j) {
      int brow = j * 16 + lr;
      bf16x8 bv = *(const bf16x8*)&Bs[cur][brow * 32 + ((lg ^ ((brow >> 1) & 3)) * 8)];
      acc[j] = mfma_bf16(av, bv, acc[j]);
    }
    __syncthreads();
  }

#pragma unroll
  for (int j = 0; j < 4; ++j) {
    int n = n0 + j * 16 + lr;
    float bsv = bias[n];
#pragma unroll
    for (int r = 0; r < 4; ++r) {
      int m = m0 + w * 16 + lg * 4 + r;
      out[(size_t)m * 512 + n] = acc[j][r] + bsv;
    }
  }
}

// ------------ flash attention, BARRIER-FREE: 1 q-tile(16 rows)/wave ------------
// K/V per (b,h) = 256KB, L2-resident (FETCH evidence r6-r9) -> read K-frags and
// V-frags DIRECTLY from global (Common-mistake #7: don't stage L2-fitting data).
// No __syncthreads/s_barrier/vmcnt anywhere; waves fully independent; P-tile in
// per-wave LDS (same-wave write->read). Grid 1024 blocks -> 16 waves/CU TLP.
// Both K and V frag loads touch 16 x 64B contiguous segments per instr.
__global__ __launch_bounds__(256, 4) void attn_kernel(
    const __bf16* __restrict__ Qh, const __bf16* __restrict__ Kh,
    const __bf16* __restrict__ Vth, const float* __restrict__ U,
    const float* __restrict__ mask, __bf16* __restrict__ ctx) {
  __shared__ __align__(16) __bf16 Ps[4][16 * 64];   // per-wave P [q][k], swizzled
  const int tid = threadIdx.x;
  const int lane = tid & 63;
  const int w = tid >> 6;
  const int lr = lane & 15, lg = lane >> 4;
  const int bh = blockIdx.x, qb = blockIdx.y;
  const int b = bh >> 3, h = bh & 7;

  const int qrow = qb * 64 + w * 16 + lr;

  // Q as B-frag (col=q=lr, k-dim d=lg*8+j)
  bf16x8 qf[2];
  {
    const __bf16* qp = Qh + ((size_t)bh * 1024 + qrow) * 64;
    qf[0] = *(const bf16x8*)(qp + lg * 8);
    qf[1] = *(const bf16x8*)(qp + 32 + lg * 8);
  }

  f32x4 acc_o[4] = {};   // acc_o[t][r] = O[q=lr][d=t*16+lg*4+r]
  float m_run = -3e38f, l_run = 0.f;

  const __bf16* Kbase = Kh + (size_t)bh * 1024 * 64;
  const __bf16* Vbase = Vth + (size_t)bh * 64 * 1024;
  const float* Uq = U + (size_t)qrow * 1024 + lg * 4;
  const float* mq = mask + b * 1024 + lg * 4;
  __bf16* pw = &Ps[w][0];

  for (int kb = 0; kb < 16; ++kb) {
    // U + mask (vector, k-consecutive per lane; L2/L3-resident)
    float4v uc[4], mc[4];
#pragma unroll
    for (int t = 0; t < 4; ++t) {
      uc[t] = *(const float4v*)(Uq + kb * 64 + t * 16);
      mc[t] = *(const float4v*)(mq + kb * 64 + t * 16);
    }

    // S^T = K Q^T, K-frags straight from global (L2)
    f32x4 sv[4];
    __builtin_amdgcn_s_setprio(1);
#pragma unroll
    for (int t = 0; t < 4; ++t) {
      int krow = t * 16 + lr;
      const __bf16* kp = Kbase + (size_t)(kb * 64 + krow) * 64;
      bf16x8 k0 = *(const bf16x8*)(kp + lg * 8);
      bf16x8 k1 = *(const bf16x8*)(kp + 32 + lg * 8);
      f32x4 z = {0.f, 0.f, 0.f, 0.f};
      z = mfma_bf16(k0, qf[0], z);
      z = mfma_bf16(k1, qf[1], z);
      sv[t] = z;
    }
    __builtin_amdgcn_s_setprio(0);

    // log2-domain scores
#pragma unroll
    for (int t = 0; t < 4; ++t)
#pragma unroll
      for (int r = 0; r < 4; ++r)
        sv[t][r] = fmaf(uc[t][r], LOG2E, fmaf(sv[t][r], ATT_SCALE2, mc[t][r] * LOG2E));

    // row max: 15 in-lane (tree) + 2 shfl
    float mt[4];
#pragma unroll
    for (int t = 0; t < 4; ++t)
      mt[t] = fmaxf(fmaxf(sv[t][0], sv[t][1]), fmaxf(sv[t][2], sv[t][3]));
    float mx = fmaxf(fmaxf(mt[0], mt[1]), fmaxf(mt[2], mt[3]));
    mx = fmaxf(mx, __shfl_xor(mx, 16));
    mx = fmaxf(mx, __shfl_xor(mx, 32));

    // T13 defer-max (log2 domain, THR=8)
    if (__any(mx > m_run + 8.f)) {
      float mnew = fmaxf(m_run, mx);
      float f = EXP2(m_run - mnew);
      m_run = mnew;
      l_run *= f;
#pragma unroll
      for (int t = 0; t < 4; ++t) acc_o[t] *= f;
    }

    // exp + row sum
    float pt[4];
#pragma unroll
    for (int t = 0; t < 4; ++t) {
#pragma unroll
      for (int r = 0; r < 4; ++r) sv[t][r] = EXP2(sv[t][r] - m_run);
      pt[t] = (sv[t][0] + sv[t][1]) + (sv[t][2] + sv[t][3]);
    }
    float ps = (pt[0] + pt[1]) + (pt[2] + pt[3]);
    ps += __shfl_xor(ps, 16);
    ps += __shfl_xor(ps, 32);
    l_run += ps;

    // P -> per-wave LDS (swizzled), 4 x 8B vector writes
#pragma unroll
    for (int t = 0; t < 4; ++t) {
      bf16x4 pk;
      pk[0] = (__bf16)sv[t][0]; pk[1] = (__bf16)sv[t][1];
      pk[2] = (__bf16)sv[t][2]; pk[3] = (__bf16)sv[t][3];
      int k0 = t * 16 + lg * 4;
      *(bf16x4*)&pw[lr * 64 + (k0 ^ ((lr & 7) << 3))] = pk;
    }

    // PV: O^T = V^T @ P^T, V-frags straight from global (L2)
    bf16x8 pa0, pa1;
    {
      const __bf16* pp = &pw[lr * 64];
      int sw = lr & 7;
      pa0 = *(const bf16x8*)(pp + ((lg ^ sw) * 8));
      pa1 = *(const bf16x8*)(pp + (((4 + lg) ^ sw) * 8));
    }
    __builtin_amdgcn_s_setprio(1);
#pragma unroll
    for (int t = 0; t < 4; ++t) {
      int vrow = t * 16 + lr;
      const __bf16* vp = Vbase + (size_t)vrow * 1024 + kb * 64;
      bf16x8 v0 = *(const bf16x8*)(vp + lg * 8);
      bf16x8 v1 = *(const bf16x8*)(vp + 32 + lg * 8);
      acc_o[t] = mfma_bf16(v0, pa0, acc_o[t]);
      acc_o[t] = mfma_bf16(v1, pa1, acc_o[t]);
    }
    __builtin_amdgcn_s_setprio(0);
  }

  // normalize + write ctx
  float inv = 1.0f / l_run;
  __bf16* cp = ctx + ((size_t)(b * 1024 + qrow)) * 512 + h * 64 + lg * 4;
#pragma unroll
  for (int t = 0; t < 4; ++t) {
    bf16x4 ov;
    ov[0] = (__bf16)(acc_o[t][0] * inv); ov[1] = (__bf16)(acc_o[t][1] * inv);
    ov[2] = (__bf16)(acc_o[t][2] * inv); ov[3] = (__bf16)(acc_o[t][3] * inv);
    *(bf16x4*)(cp + t * 16) = ov;
  }
}

extern "C" void kernel_launch(void* const* d_in, const int* in_sizes, int n_in,
                              void* d_out, int out_size, void* d_ws, size_t ws_size,
                              hipStream_t stream) {
  (void)in_sizes; (void)n_in; (void)out_size; (void)ws_size;
  const float* x     = (const float*)d_in[0];
  const float* U     = (const float*)d_in[1];
  const float* mask  = (const float*)d_in[2];
  const float* w_qkv = (const float*)d_in[3];
  const float* b_qkv = (const float*)d_in[4];
  const float* w_out = (const float*)d_in[5];
  const float* b_out = (const float*)d_in[6];
  float* out = (float*)d_out;

  char* p = (char*)d_ws;
  __bf16* xb    = (__bf16*)p; p += (size_t)8192 * 512 * 2;
  __bf16* wqkvT = (__bf16*)p; p += (size_t)1536 * 512 * 2;
  __bf16* woutT = (__bf16*)p; p += (size_t)512 * 512 * 2;
  __bf16* Qh    = (__bf16*)p; p += (size_t)64 * 1024 * 64 * 2;
  __bf16* Kh    = (__bf16*)p; p += (size_t)64 * 1024 * 64 * 2;
  __bf16* Vth   = (__bf16*)p; p += (size_t)64 * 64 * 1024 * 2;
  __bf16* ctx   = (__bf16*)p; p += (size_t)8192 * 512 * 2;

  hipLaunchKernelGGL(cast_x_kernel, dim3(2048), dim3(256), 0, stream,
                     x, xb, 8192 * 512 / 4);
  hipLaunchKernelGGL(transpose_both_kernel, dim3(64, 16), dim3(32, 8), 0, stream,
                     w_qkv, w_out, wqkvT, woutT);
  hipLaunchKernelGGL(gemm_qkv_kernel, dim3(64, 12), dim3(256), 0, stream,
                     xb, wqkvT, b_qkv, Qh, Kh, Vth);
  hipLaunchKernelGGL(attn_kernel, dim3(64, 16), dim3(256), 0, stream,
                     Qh, Kh, Vth, U, mask, ctx);
  hipLaunchKernelGGL(gemm_out_kernel, dim3(128, 8), dim3(256), 0, stream,
                     ctx, woutT, b_out, out);
}

// Round 11
// 113.381 us; speedup vs baseline: 1.7602x; 1.7602x over previous
//
#include <hip/hip_runtime.h>

#define DEV __device__ __forceinline__

typedef __attribute__((ext_vector_type(8))) __bf16 bf16x8;
typedef __attribute__((ext_vector_type(4))) __bf16 bf16x4;
typedef __attribute__((ext_vector_type(4))) float f32x4;
typedef __attribute__((ext_vector_type(4))) float float4v;

typedef __attribute__((address_space(1))) const void ga_void;
typedef __attribute__((address_space(3))) void la_void;

constexpr float LOG2E = 1.44269504089f;
constexpr float ATT_SCALE2 = 0.125f * 1.44269504089f;  // 1/sqrt(64) * log2(e)

#if __has_builtin(__builtin_amdgcn_exp2f)
#define EXP2(x) __builtin_amdgcn_exp2f(x)
#else
#define EXP2(x) exp2f(x)
#endif

DEV void gload16(const void* g, void* l) {
  __builtin_amdgcn_global_load_lds((ga_void*)g, (la_void*)l, 16, 0, 0);
}

DEV f32x4 mfma_bf16(bf16x8 a, bf16x8 b, f32x4 c) {
  return __builtin_amdgcn_mfma_f32_16x16x32_bf16(a, b, c, 0, 0, 0);
}

// ---------------- cast x (f32 -> bf16), vectorized ----------------
__global__ __launch_bounds__(256) void cast_x_kernel(
    const float* __restrict__ in, __bf16* __restrict__ out, int n4) {
  int i = blockIdx.x * blockDim.x + threadIdx.x;
  int stride = gridDim.x * blockDim.x;
  for (; i < n4; i += stride) {
    float4v v = ((const float4v*)in)[i];
    bf16x4 o;
    o[0] = (__bf16)v[0]; o[1] = (__bf16)v[1];
    o[2] = (__bf16)v[2]; o[3] = (__bf16)v[3];
    ((bf16x4*)out)[i] = o;
  }
}

// ---- fused transpose+cast of BOTH weights: f32 [512][Nc] -> bf16 [Nc][512] ----
__global__ __launch_bounds__(256) void transpose_both_kernel(
    const float* __restrict__ wqkv, const float* __restrict__ wout,
    __bf16* __restrict__ wqkvT, __bf16* __restrict__ woutT) {
  __shared__ float tile[32][33];
  const float* in;
  __bf16* out;
  int Nc, bx;
  if (blockIdx.x < 48) { in = wqkv; out = wqkvT; Nc = 1536; bx = blockIdx.x * 32; }
  else                 { in = wout; out = woutT; Nc = 512;  bx = (blockIdx.x - 48) * 32; }
  int by = blockIdx.y * 32;
  int tx = threadIdx.x, ty = threadIdx.y;
#pragma unroll
  for (int i = ty; i < 32; i += 8)
    tile[i][tx] = in[(size_t)(by + i) * Nc + bx + tx];
  __syncthreads();
#pragma unroll
  for (int i = ty; i < 32; i += 8)
    out[(size_t)(bx + i) * 512 + by + tx] = (__bf16)tile[tx][i];
}

// ---------------- GEMM1: xb[8192x512] @ wqkvT^T -> split Q/K/Vt ----------------
__global__ __launch_bounds__(256) void gemm_qkv_kernel(
    const __bf16* __restrict__ A, const __bf16* __restrict__ Bt,
    const float* __restrict__ bias,
    __bf16* __restrict__ Qo, __bf16* __restrict__ Ko, __bf16* __restrict__ Vto) {
  __shared__ __align__(16) __bf16 As[2][128 * 32];
  __shared__ __align__(16) __bf16 Bs[2][128 * 32];
  const int tid = threadIdx.x;
  const int lane = tid & 63;
  const int w = tid >> 6;
  const int lr = lane & 15, lg = lane >> 4;
  const int m0 = blockIdx.x * 128, n0 = blockIdx.y * 128;
  const int wr = w >> 1, wc = w & 1;

  f32x4 acc[4][4] = {};

  auto stage = [&](int buf, int kt) {
#pragma unroll
    for (int cc = 0; cc < 2; ++cc) {
      int c = w * 2 + cc;
      int row = c * 16 + (lane >> 2);
      int slot = (lane & 3) ^ ((row >> 1) & 3);
      gload16(A + (size_t)(m0 + row) * 512 + kt * 32 + slot * 8, &As[buf][c * 512]);
      gload16(Bt + (size_t)(n0 + row) * 512 + kt * 32 + slot * 8, &Bs[buf][c * 512]);
    }
  };

  stage(0, 0);
  __syncthreads();
  for (int kt = 0; kt < 16; ++kt) {
    int cur = kt & 1;
    if (kt < 15) stage(cur ^ 1, kt + 1);
    bf16x8 av[4], bv[4];
#pragma unroll
    for (int i = 0; i < 4; ++i) {
      int row = wr * 64 + i * 16 + lr;
      av[i] = *(const bf16x8*)&As[cur][row * 32 + ((lg ^ ((row >> 1) & 3)) * 8)];
    }
#pragma unroll
    for (int j = 0; j < 4; ++j) {
      int row = wc * 64 + j * 16 + lr;
      bv[j] = *(const bf16x8*)&Bs[cur][row * 32 + ((lg ^ ((row >> 1) & 3)) * 8)];
    }
#pragma unroll
    for (int i = 0; i < 4; ++i)
#pragma unroll
      for (int j = 0; j < 4; ++j)
        acc[i][j] = mfma_bf16(av[i], bv[j], acc[i][j]);
    __syncthreads();
  }

  const int sec = n0 >> 9;
#pragma unroll
  for (int j = 0; j < 4; ++j) {
    int n = n0 + wc * 64 + j * 16 + lr;
    float bsv = bias[n];
    int nn = n & 511;
    int h = nn >> 6, d = nn & 63;
#pragma unroll
    for (int i = 0; i < 4; ++i) {
#pragma unroll
      for (int r = 0; r < 4; ++r) {
        int m = m0 + wr * 64 + i * 16 + lg * 4 + r;
        int b = m >> 10, nr = m & 1023;
        float v = acc[i][j][r] + bsv;
        if (sec == 0)
          Qo[(((size_t)(b * 8 + h)) * 1024 + nr) * 64 + d] = (__bf16)v;
        else if (sec == 1)
          Ko[(((size_t)(b * 8 + h)) * 1024 + nr) * 64 + d] = (__bf16)v;
        else
          Vto[(((size_t)(b * 8 + h)) * 64 + d) * 1024 + nr] = (__bf16)v;
      }
    }
  }
}

// ------- GEMM2: ctx[8192x512] @ woutT^T + b_out -> f32 out; 64x64 tile -------
__global__ __launch_bounds__(256) void gemm_out_kernel(
    const __bf16* __restrict__ A, const __bf16* __restrict__ Bt,
    const float* __restrict__ bias, float* __restrict__ out) {
  __shared__ __align__(16) __bf16 As[2][64 * 32];
  __shared__ __align__(16) __bf16 Bs[2][64 * 32];
  const int tid = threadIdx.x;
  const int lane = tid & 63;
  const int w = tid >> 6;
  const int lr = lane & 15, lg = lane >> 4;
  const int m0 = blockIdx.x * 64, n0 = blockIdx.y * 64;

  f32x4 acc[4] = {};

  auto stage = [&](int buf, int kt) {
    int row = tid >> 2;
    int sg = (tid & 3) ^ ((row >> 1) & 3);
    gload16(A + (size_t)(m0 + row) * 512 + kt * 32 + sg * 8, &As[buf][tid * 8]);
    gload16(Bt + (size_t)(n0 + row) * 512 + kt * 32 + sg * 8, &Bs[buf][tid * 8]);
  };

  stage(0, 0);
  __syncthreads();
  for (int kt = 0; kt < 16; ++kt) {
    int cur = kt & 1;
    if (kt < 15) stage(cur ^ 1, kt + 1);
    int arow = w * 16 + lr;
    bf16x8 av = *(const bf16x8*)&As[cur][arow * 32 + ((lg ^ ((arow >> 1) & 3)) * 8)];
#pragma unroll
    for (int j = 0; j < 4; ++j) {
      int brow = j * 16 + lr;
      bf16x8 bv = *(const bf16x8*)&Bs[cur][brow * 32 + ((lg ^ ((brow >> 1) & 3)) * 8)];
      acc[j] = mfma_bf16(av, bv, acc[j]);
    }
    __syncthreads();
  }

#pragma unroll
  for (int j = 0; j < 4; ++j) {
    int n = n0 + j * 16 + lr;
    float bsv = bias[n];
#pragma unroll
    for (int r = 0; r < 4; ++r) {
      int m = m0 + w * 16 + lg * 4 + r;
      out[(size_t)m * 512 + n] = acc[j][r] + bsv;
    }
  }
}

// ---------- flash attention: WAVE-PRIVATE staging, ZERO barriers ----------
// Each wave owns 2 q-tiles (16 rows each) and stages its OWN K/V (KBLK=32,
// dbuf) into a private LDS region via global_load_lds; counted vmcnt(14/6)
// (T4) keeps next-tile loads in flight; NO s_barrier/__syncthreads anywhere.
// 8 waves/CU self-schedule -> latencies overlap across desynced waves.
// LDS: K 32K + V 32K + P 16K = 80KB -> 2 blocks/CU; grid (64,8)=512.
__global__ __launch_bounds__(256, 2) void attn_kernel(
    const __bf16* __restrict__ Qh, const __bf16* __restrict__ Kh,
    const __bf16* __restrict__ Vth, const float* __restrict__ U,
    const float* __restrict__ mask, __bf16* __restrict__ ctx) {
  __shared__ __align__(16) __bf16 Ks[4][2][32 * 64];   // per-wave [k][d]
  __shared__ __align__(16) __bf16 Vs[4][2][64 * 32];   // per-wave [d][k]
  __shared__ __align__(16) __bf16 Ps[4][2][16 * 64];   // per-wave per-item P
  const int tid = threadIdx.x;
  const int lane = tid & 63;
  const int w = tid >> 6;
  const int lr = lane & 15, lg = lane >> 4;
  const int bh = blockIdx.x, qp = blockIdx.y;
  const int b = bh >> 3, h = bh & 7;

  int qrow[2];
  qrow[0] = qp * 64 + w * 16 + lr;
  qrow[1] = (qp + 8) * 64 + w * 16 + lr;

  bf16x8 qf[2][2];
#pragma unroll
  for (int it = 0; it < 2; ++it) {
    const __bf16* qpt = Qh + ((size_t)bh * 1024 + qrow[it]) * 64;
    qf[it][0] = *(const bf16x8*)(qpt + lg * 8);
    qf[it][1] = *(const bf16x8*)(qpt + 32 + lg * 8);
  }

  f32x4 acc_o[2][4] = {};
  float m_run[2] = {-3e38f, -3e38f}, l_run[2] = {0.f, 0.f};

  // per-wave staging: K tile [32][64] (8 slots/row, slot^=row&7);
  //                   V tile [64][32] (4 slots/row, slot-=(row>>1)&3)
  auto stageKV = [&](int buf, int kb) {
#pragma unroll
    for (int i = 0; i < 4; ++i) {
      int g = i * 64 + lane;
      int row = g >> 3, slot = g & 7;
      int sg = slot ^ (row & 7);
      gload16(Kh + ((size_t)bh * 1024 + kb * 32 + row) * 64 + sg * 8,
              &Ks[w][buf][i * 512]);
    }
#pragma unroll
    for (int i = 0; i < 4; ++i) {
      int g = i * 64 + lane;
      int row = g >> 2, slot = g & 3;
      int c = (slot - ((row >> 1) & 3)) & 3;
      gload16(Vth + ((size_t)bh * 64 + row) * 1024 + kb * 32 + c * 8,
              &Vs[w][buf][i * 512]);
    }
  };

  const float* Uq0 = U + (size_t)qrow[0] * 1024 + lg * 4;
  const float* Uq1 = U + (size_t)qrow[1] * 1024 + lg * 4;
  const float* mq = mask + b * 1024 + lg * 4;

  // prologue: stage tile 0 (own region, own wait, no barrier)
  stageKV(0, 0);

  for (int kb = 0; kb < 32; ++kb) {
    const int cur = kb & 1;

    // 1) U/mask for THIS iter (issued before stage so compiler's U-wait
    //    leaves the stage loads in flight)
    float4v uc[2][2], mc[2];
#pragma unroll
    for (int t = 0; t < 2; ++t) {
      mc[t] = *(const float4v*)(mq + kb * 32 + t * 16);
      uc[0][t] = *(const float4v*)(Uq0 + kb * 32 + t * 16);
      uc[1][t] = *(const float4v*)(Uq1 + kb * 32 + t * 16);
    }
    __builtin_amdgcn_sched_barrier(0);

    // 2) stage NEXT tile (8 loads), then counted wait: drain only stage(kb)
    if (kb < 31) {
      stageKV(cur ^ 1, kb + 1);
      __builtin_amdgcn_sched_barrier(0);
      asm volatile("s_waitcnt vmcnt(14)" ::: "memory");  // 6 U/mask + 8 stage in flight
    } else {
      __builtin_amdgcn_sched_barrier(0);
      asm volatile("s_waitcnt vmcnt(6)" ::: "memory");   // 6 U/mask in flight
    }
    __builtin_amdgcn_sched_barrier(0);

    // 3) QK: S^T = K Q^T (K-frags from own LDS region)
    f32x4 sv[2][2];
    __builtin_amdgcn_s_setprio(1);
#pragma unroll
    for (int t = 0; t < 2; ++t) {
      int krow = t * 16 + lr;
      const __bf16* kp = &Ks[w][cur][krow * 64];
      int sw = krow & 7;
      bf16x8 k0 = *(const bf16x8*)(kp + ((lg ^ sw) * 8));
      bf16x8 k1 = *(const bf16x8*)(kp + (((4 + lg) ^ sw) * 8));
#pragma unroll
      for (int it = 0; it < 2; ++it) {
        f32x4 z = {0.f, 0.f, 0.f, 0.f};
        z = mfma_bf16(k0, qf[it][0], z);
        z = mfma_bf16(k1, qf[it][1], z);
        sv[it][t] = z;
      }
    }
    __builtin_amdgcn_s_setprio(0);

    // 4) softmax per item (log2 domain, defer-max)
#pragma unroll
    for (int it = 0; it < 2; ++it) {
#pragma unroll
      for (int t = 0; t < 2; ++t)
#pragma unroll
        for (int r = 0; r < 4; ++r)
          sv[it][t][r] =
              fmaf(uc[it][t][r], LOG2E, fmaf(sv[it][t][r], ATT_SCALE2, mc[t][r] * LOG2E));

      float m01 = fmaxf(fmaxf(sv[it][0][0], sv[it][0][1]), fmaxf(sv[it][0][2], sv[it][0][3]));
      float m23 = fmaxf(fmaxf(sv[it][1][0], sv[it][1][1]), fmaxf(sv[it][1][2], sv[it][1][3]));
      float mx = fmaxf(m01, m23);
      mx = fmaxf(mx, __shfl_xor(mx, 16));
      mx = fmaxf(mx, __shfl_xor(mx, 32));

      if (__any(mx > m_run[it] + 8.f)) {
        float mnew = fmaxf(m_run[it], mx);
        float f = EXP2(m_run[it] - mnew);
        m_run[it] = mnew;
        l_run[it] *= f;
#pragma unroll
        for (int t = 0; t < 4; ++t) acc_o[it][t] *= f;
      }

      float pt[2];
#pragma unroll
      for (int t = 0; t < 2; ++t) {
#pragma unroll
        for (int r = 0; r < 4; ++r) sv[it][t][r] = EXP2(sv[it][t][r] - m_run[it]);
        pt[t] = (sv[it][t][0] + sv[it][t][1]) + (sv[it][t][2] + sv[it][t][3]);
      }
      float ps = pt[0] + pt[1];
      ps += __shfl_xor(ps, 16);
      ps += __shfl_xor(ps, 32);
      l_run[it] += ps;

      // P -> own LDS (swizzled 8B writes); k<32 occupies half the 64-wide row
      __bf16* pw = &Ps[w][it][0];
#pragma unroll
      for (int t = 0; t < 2; ++t) {
        bf16x4 pk;
        pk[0] = (__bf16)sv[it][t][0]; pk[1] = (__bf16)sv[it][t][1];
        pk[2] = (__bf16)sv[it][t][2]; pk[3] = (__bf16)sv[it][t][3];
        int k0i = t * 16 + lg * 4;
        *(bf16x4*)&pw[lr * 64 + (k0i ^ ((lr & 7) << 3))] = pk;
      }
    }

    // 5) PV: O^T += V^T @ P^T (V-frags from own LDS region; k-dim = 32)
    bf16x8 pa[2];
#pragma unroll
    for (int it = 0; it < 2; ++it) {
      const __bf16* pp = &Ps[w][it][lr * 64];
      pa[it] = *(const bf16x8*)(pp + ((lg ^ (lr & 7)) * 8));
    }
    __builtin_amdgcn_s_setprio(1);
#pragma unroll
    for (int t = 0; t < 4; ++t) {
      int vrow = t * 16 + lr;
      int vs = (lg + ((vrow >> 1) & 3)) & 3;
      bf16x8 vf = *(const bf16x8*)(&Vs[w][cur][vrow * 32 + vs * 8]);
#pragma unroll
      for (int it = 0; it < 2; ++it)
        acc_o[it][t] = mfma_bf16(vf, pa[it], acc_o[it][t]);
    }
    __builtin_amdgcn_s_setprio(0);
  }

  // normalize + write ctx per item
#pragma unroll
  for (int it = 0; it < 2; ++it) {
    float inv = 1.0f / l_run[it];
    __bf16* cp = ctx + ((size_t)(b * 1024 + qrow[it])) * 512 + h * 64 + lg * 4;
#pragma unroll
    for (int t = 0; t < 4; ++t) {
      bf16x4 ov;
      ov[0] = (__bf16)(acc_o[it][t][0] * inv); ov[1] = (__bf16)(acc_o[it][t][1] * inv);
      ov[2] = (__bf16)(acc_o[it][t][2] * inv); ov[3] = (__bf16)(acc_o[it][t][3] * inv);
      *(bf16x4*)(cp + t * 16) = ov;
    }
  }
}

extern "C" void kernel_launch(void* const* d_in, const int* in_sizes, int n_in,
                              void* d_out, int out_size, void* d_ws, size_t ws_size,
                              hipStream_t stream) {
  (void)in_sizes; (void)n_in; (void)out_size; (void)ws_size;
  const float* x     = (const float*)d_in[0];
  const float* U     = (const float*)d_in[1];
  const float* mask  = (const float*)d_in[2];
  const float* w_qkv = (const float*)d_in[3];
  const float* b_qkv = (const float*)d_in[4];
  const float* w_out = (const float*)d_in[5];
  const float* b_out = (const float*)d_in[6];
  float* out = (float*)d_out;

  char* p = (char*)d_ws;
  __bf16* xb    = (__bf16*)p; p += (size_t)8192 * 512 * 2;
  __bf16* wqkvT = (__bf16*)p; p += (size_t)1536 * 512 * 2;
  __bf16* woutT = (__bf16*)p; p += (size_t)512 * 512 * 2;
  __bf16* Qh    = (__bf16*)p; p += (size_t)64 * 1024 * 64 * 2;
  __bf16* Kh    = (__bf16*)p; p += (size_t)64 * 1024 * 64 * 2;
  __bf16* Vth   = (__bf16*)p; p += (size_t)64 * 64 * 1024 * 2;
  __bf16* ctx   = (__bf16*)p; p += (size_t)8192 * 512 * 2;

  hipLaunchKernelGGL(cast_x_kernel, dim3(2048), dim3(256), 0, stream,
                     x, xb, 8192 * 512 / 4);
  hipLaunchKernelGGL(transpose_both_kernel, dim3(64, 16), dim3(32, 8), 0, stream,
                     w_qkv, w_out, wqkvT, woutT);
  hipLaunchKernelGGL(gemm_qkv_kernel, dim3(64, 12), dim3(256), 0, stream,
                     xb, wqkvT, b_qkv, Qh, Kh, Vth);
  hipLaunchKernelGGL(attn_kernel, dim3(64, 8), dim3(256), 0, stream,
                     Qh, Kh, Vth, U, mask, ctx);
  hipLaunchKernelGGL(gemm_out_kernel, dim3(128, 8), dim3(256), 0, stream,
                     ctx, woutT, b_out, out);
}

// Round 12
// 98.222 us; speedup vs baseline: 2.0318x; 1.1543x over previous
//
#include <hip/hip_runtime.h>

#define DEV __device__ __forceinline__

typedef __attribute__((ext_vector_type(8))) __bf16 bf16x8;
typedef __attribute__((ext_vector_type(4))) __bf16 bf16x4;
typedef __attribute__((ext_vector_type(4))) float f32x4;
typedef __attribute__((ext_vector_type(16))) float f32x16;
typedef __attribute__((ext_vector_type(4))) float float4v;
typedef __attribute__((ext_vector_type(4))) int int4v;

typedef __attribute__((address_space(1))) const void ga_void;
typedef __attribute__((address_space(3))) void la_void;

constexpr float LOG2E = 1.44269504089f;
constexpr float ATT_SCALE2 = 0.125f * 1.44269504089f;  // 1/sqrt(64) * log2(e)

#if __has_builtin(__builtin_amdgcn_exp2f)
#define EXP2(x) __builtin_amdgcn_exp2f(x)
#else
#define EXP2(x) exp2f(x)
#endif

DEV void gload16(const void* g, void* l) {
  __builtin_amdgcn_global_load_lds((ga_void*)g, (la_void*)l, 16, 0, 0);
}

DEV f32x4 mfma_bf16(bf16x8 a, bf16x8 b, f32x4 c) {
  return __builtin_amdgcn_mfma_f32_16x16x32_bf16(a, b, c, 0, 0, 0);
}

DEV f32x16 mfma32(bf16x8 a, bf16x8 b, f32x16 c) {
  return __builtin_amdgcn_mfma_f32_32x32x16_bf16(a, b, c, 0, 0, 0);
}

DEV unsigned cvt_pk(float lo, float hi) {
  unsigned r;
  asm("v_cvt_pk_bf16_f32 %0, %1, %2" : "=v"(r) : "v"(lo), "v"(hi));
  return r;
}

// ---------------- cast x (f32 -> bf16), vectorized ----------------
__global__ __launch_bounds__(256) void cast_x_kernel(
    const float* __restrict__ in, __bf16* __restrict__ out, int n4) {
  int i = blockIdx.x * blockDim.x + threadIdx.x;
  int stride = gridDim.x * blockDim.x;
  for (; i < n4; i += stride) {
    float4v v = ((const float4v*)in)[i];
    bf16x4 o;
    o[0] = (__bf16)v[0]; o[1] = (__bf16)v[1];
    o[2] = (__bf16)v[2]; o[3] = (__bf16)v[3];
    ((bf16x4*)out)[i] = o;
  }
}

// ---- fused transpose+cast of BOTH weights: f32 [512][Nc] -> bf16 [Nc][512] ----
__global__ __launch_bounds__(256) void transpose_both_kernel(
    const float* __restrict__ wqkv, const float* __restrict__ wout,
    __bf16* __restrict__ wqkvT, __bf16* __restrict__ woutT) {
  __shared__ float tile[32][33];
  const float* in;
  __bf16* out;
  int Nc, bx;
  if (blockIdx.x < 48) { in = wqkv; out = wqkvT; Nc = 1536; bx = blockIdx.x * 32; }
  else                 { in = wout; out = woutT; Nc = 512;  bx = (blockIdx.x - 48) * 32; }
  int by = blockIdx.y * 32;
  int tx = threadIdx.x, ty = threadIdx.y;
#pragma unroll
  for (int i = ty; i < 32; i += 8)
    tile[i][tx] = in[(size_t)(by + i) * Nc + bx + tx];
  __syncthreads();
#pragma unroll
  for (int i = ty; i < 32; i += 8)
    out[(size_t)(bx + i) * 512 + by + tx] = (__bf16)tile[tx][i];
}

// ---------------- GEMM1: xb[8192x512] @ wqkvT^T -> split Q/K/Vt ----------------
__global__ __launch_bounds__(256) void gemm_qkv_kernel(
    const __bf16* __restrict__ A, const __bf16* __restrict__ Bt,
    const float* __restrict__ bias,
    __bf16* __restrict__ Qo, __bf16* __restrict__ Ko, __bf16* __restrict__ Vto) {
  __shared__ __align__(16) __bf16 As[2][128 * 32];
  __shared__ __align__(16) __bf16 Bs[2][128 * 32];
  const int tid = threadIdx.x;
  const int lane = tid & 63;
  const int w = tid >> 6;
  const int lr = lane & 15, lg = lane >> 4;
  const int m0 = blockIdx.x * 128, n0 = blockIdx.y * 128;
  const int wr = w >> 1, wc = w & 1;

  f32x4 acc[4][4] = {};

  auto stage = [&](int buf, int kt) {
#pragma unroll
    for (int cc = 0; cc < 2; ++cc) {
      int c = w * 2 + cc;
      int row = c * 16 + (lane >> 2);
      int slot = (lane & 3) ^ ((row >> 1) & 3);
      gload16(A + (size_t)(m0 + row) * 512 + kt * 32 + slot * 8, &As[buf][c * 512]);
      gload16(Bt + (size_t)(n0 + row) * 512 + kt * 32 + slot * 8, &Bs[buf][c * 512]);
    }
  };

  stage(0, 0);
  __syncthreads();
  for (int kt = 0; kt < 16; ++kt) {
    int cur = kt & 1;
    if (kt < 15) stage(cur ^ 1, kt + 1);
    bf16x8 av[4], bv[4];
#pragma unroll
    for (int i = 0; i < 4; ++i) {
      int row = wr * 64 + i * 16 + lr;
      av[i] = *(const bf16x8*)&As[cur][row * 32 + ((lg ^ ((row >> 1) & 3)) * 8)];
    }
#pragma unroll
    for (int j = 0; j < 4; ++j) {
      int row = wc * 64 + j * 16 + lr;
      bv[j] = *(const bf16x8*)&Bs[cur][row * 32 + ((lg ^ ((row >> 1) & 3)) * 8)];
    }
#pragma unroll
    for (int i = 0; i < 4; ++i)
#pragma unroll
      for (int j = 0; j < 4; ++j)
        acc[i][j] = mfma_bf16(av[i], bv[j], acc[i][j]);
    __syncthreads();
  }

  const int sec = n0 >> 9;
#pragma unroll
  for (int j = 0; j < 4; ++j) {
    int n = n0 + wc * 64 + j * 16 + lr;
    float bsv = bias[n];
    int nn = n & 511;
    int h = nn >> 6, d = nn & 63;
#pragma unroll
    for (int i = 0; i < 4; ++i) {
#pragma unroll
      for (int r = 0; r < 4; ++r) {
        int m = m0 + wr * 64 + i * 16 + lg * 4 + r;
        int b = m >> 10, nr = m & 1023;
        float v = acc[i][j][r] + bsv;
        if (sec == 0)
          Qo[(((size_t)(b * 8 + h)) * 1024 + nr) * 64 + d] = (__bf16)v;
        else if (sec == 1)
          Ko[(((size_t)(b * 8 + h)) * 1024 + nr) * 64 + d] = (__bf16)v;
        else
          Vto[(((size_t)(b * 8 + h)) * 64 + d) * 1024 + nr] = (__bf16)v;
      }
    }
  }
}

// ------- GEMM2: ctx[8192x512] @ woutT^T + b_out -> f32 out; 64x64 tile -------
__global__ __launch_bounds__(256) void gemm_out_kernel(
    const __bf16* __restrict__ A, const __bf16* __restrict__ Bt,
    const float* __restrict__ bias, float* __restrict__ out) {
  __shared__ __align__(16) __bf16 As[2][64 * 32];
  __shared__ __align__(16) __bf16 Bs[2][64 * 32];
  const int tid = threadIdx.x;
  const int lane = tid & 63;
  const int w = tid >> 6;
  const int lr = lane & 15, lg = lane >> 4;
  const int m0 = blockIdx.x * 64, n0 = blockIdx.y * 64;

  f32x4 acc[4] = {};

  auto stage = [&](int buf, int kt) {
    int row = tid >> 2;
    int sg = (tid & 3) ^ ((row >> 1) & 3);
    gload16(A + (size_t)(m0 + row) * 512 + kt * 32 + sg * 8, &As[buf][tid * 8]);
    gload16(Bt + (size_t)(n0 + row) * 512 + kt * 32 + sg * 8, &Bs[buf][tid * 8]);
  };

  stage(0, 0);
  __syncthreads();
  for (int kt = 0; kt < 16; ++kt) {
    int cur = kt & 1;
    if (kt < 15) stage(cur ^ 1, kt + 1);
    int arow = w * 16 + lr;
    bf16x8 av = *(const bf16x8*)&As[cur][arow * 32 + ((lg ^ ((arow >> 1) & 3)) * 8)];
#pragma unroll
    for (int j = 0; j < 4; ++j) {
      int brow = j * 16 + lr;
      bf16x8 bv = *(const bf16x8*)&Bs[cur][brow * 32 + ((lg ^ ((brow >> 1) & 3)) * 8)];
      acc[j] = mfma_bf16(av, bv, acc[j]);
    }
    __syncthreads();
  }

#pragma unroll
  for (int j = 0; j < 4; ++j) {
    int n = n0 + j * 16 + lr;
    float bsv = bias[n];
#pragma unroll
    for (int r = 0; r < 4; ++r) {
      int m = m0 + w * 16 + lg * 4 + r;
      out[(size_t)m * 512 + n] = acc[j][r] + bsv;
    }
  }
}

// --------- flash attention, 32x32 MFMA, in-register P (no P LDS) ---------
// Block = 2 waves x 32 q-rows; grid (64,16)=1024 -> 4 blocks/CU.
// Swapped QK: S^T = K.Q^T via mfma_32x32x16 (4 QK + 4 PV mfma per 32-k tile).
// C/D layout: col q = lane&31, row k = (r&3)+8*(r>>2)+4*(lane>>5) [m74/m101].
// P -> PV B-frag built in-register: 8 cvt_pk + 4 v_permlane32_swap (T12):
// with A=c[2ks],B=c[2ks+1], swap yields [own-quad, partner-quad] ascending-k
// for BOTH lane halves. K/V in 4-buffer LDS ring (32KB), r9 window schedule.
__global__ __launch_bounds__(128, 2) void attn_kernel(
    const __bf16* __restrict__ Qh, const __bf16* __restrict__ Kh,
    const __bf16* __restrict__ Vth, const float* __restrict__ U,
    const float* __restrict__ mask, __bf16* __restrict__ ctx) {
  __shared__ __align__(16) __bf16 Ks[4][32 * 64];   // [k][d], slot^=(row&7)
  __shared__ __align__(16) __bf16 Vs[4][64 * 32];   // [d][k], slot^=((row>>1)&3)
  const int tid = threadIdx.x;
  const int lane = tid & 63;
  const int w = tid >> 6;        // 0..1
  const int lq = lane & 31;      // q col within wave tile
  const int hh = lane >> 5;      // lane half
  const int bh = blockIdx.x, qb = blockIdx.y;
  const int b = bh >> 3, h = bh & 7;
  const int qrow = qb * 64 + w * 32 + lq;

  // Q B-frags: qf[step] covers d = step*16 + hh*8 + j
  bf16x8 qf[4];
  {
    const __bf16* qp = Qh + ((size_t)bh * 1024 + qrow) * 64 + hh * 8;
#pragma unroll
    for (int s = 0; s < 4; ++s) qf[s] = *(const bf16x8*)(qp + s * 16);
  }

  f32x16 acc0 = {}, acc1 = {};   // O[q=lq][d = 32*dt + (r&3)+8*(r>>2)+4*hh]
  float m_run = -3e38f, l_run = 0.f;

  auto stage = [&](int buf, int kb) {
#pragma unroll
    for (int i = 0; i < 2; ++i) {
      int g = i * 128 + tid;
      int kr = g >> 3, ksl = g & 7;
      int sg = ksl ^ (kr & 7);
      gload16(Kh + ((size_t)bh * 1024 + kb * 32 + kr) * 64 + sg * 8, &Ks[buf][g * 8]);
      int vr = g >> 2, vsl = g & 3;
      int sc = vsl ^ ((vr >> 1) & 3);
      gload16(Vth + ((size_t)bh * 64 + vr) * 1024 + kb * 32 + sc * 8, &Vs[buf][g * 8]);
    }
  };

  const float* Uq = U + (size_t)qrow * 1024 + hh * 4;
  const float* mq = mask + b * 1024 + hh * 4;

  auto processTile = [&](int kb, const __bf16* Kb, const __bf16* Vb) {
    // U + mask: k = kb*32 + rg*8 + hh*4 + ri
    float4v uc[4], mc[4];
#pragma unroll
    for (int rg = 0; rg < 4; ++rg) {
      uc[rg] = *(const float4v*)(Uq + kb * 32 + rg * 8);
      mc[rg] = *(const float4v*)(mq + kb * 32 + rg * 8);
    }

    // QK: S^T = K.Q^T, contraction over d in 4 steps of 16
    f32x16 sv = {};
    __builtin_amdgcn_s_setprio(1);
#pragma unroll
    for (int s = 0; s < 4; ++s) {
      const __bf16* kp = &Kb[lq * 64 + (((s * 2 + hh) ^ (lq & 7)) * 8)];
      sv = mfma32(*(const bf16x8*)kp, qf[s], sv);
    }
    __builtin_amdgcn_s_setprio(0);

    // scores (log2 domain): reg r -> k = (r&3)+8*(r>>2)+4*hh
    float s16[16];
#pragma unroll
    for (int rg = 0; rg < 4; ++rg)
#pragma unroll
      for (int ri = 0; ri < 4; ++ri)
        s16[rg * 4 + ri] =
            fmaf(uc[rg][ri], LOG2E, fmaf(sv[rg * 4 + ri], ATT_SCALE2, mc[rg][ri] * LOG2E));

    // row max: tree over 16 + 1 shfl (row split across lane l and l^32)
    float a0 = fmaxf(fmaxf(s16[0], s16[1]), fmaxf(s16[2], s16[3]));
    float a1 = fmaxf(fmaxf(s16[4], s16[5]), fmaxf(s16[6], s16[7]));
    float a2 = fmaxf(fmaxf(s16[8], s16[9]), fmaxf(s16[10], s16[11]));
    float a3 = fmaxf(fmaxf(s16[12], s16[13]), fmaxf(s16[14], s16[15]));
    float mx = fmaxf(fmaxf(a0, a1), fmaxf(a2, a3));
    mx = fmaxf(mx, __shfl_xor(mx, 32));

    // T13 defer-max (log2 domain, THR=8)
    if (__any(mx > m_run + 8.f)) {
      float mnew = fmaxf(m_run, mx);
      float f = EXP2(m_run - mnew);
      m_run = mnew;
      l_run *= f;
      acc0 *= f;
      acc1 *= f;
    }

    // exp + row sum
    float pt[4];
#pragma unroll
    for (int rg = 0; rg < 4; ++rg) {
#pragma unroll
      for (int ri = 0; ri < 4; ++ri) s16[rg * 4 + ri] = EXP2(s16[rg * 4 + ri] - m_run);
      pt[rg] = (s16[rg * 4] + s16[rg * 4 + 1]) + (s16[rg * 4 + 2] + s16[rg * 4 + 3]);
    }
    float ps = (pt[0] + pt[1]) + (pt[2] + pt[3]);
    ps += __shfl_xor(ps, 32);
    l_run += ps;

    // pack P quads: c[rg] = packed (k=8rg+4hh+{0,1}, {2,3})
    unsigned c[4][2];
#pragma unroll
    for (int rg = 0; rg < 4; ++rg) {
      c[rg][0] = cvt_pk(s16[rg * 4], s16[rg * 4 + 1]);
      c[rg][1] = cvt_pk(s16[rg * 4 + 2], s16[rg * 4 + 3]);
    }
    // PV B-frags via permlane32_swap: frag[ks] k = 16ks + 8hh + j
    bf16x8 pf[2];
#pragma unroll
    for (int ks = 0; ks < 2; ++ks) {
      unsigned A0 = c[2 * ks][0], A1 = c[2 * ks][1];
      unsigned B0 = c[2 * ks + 1][0], B1 = c[2 * ks + 1][1];
      asm volatile("v_permlane32_swap_b32 %0, %1" : "+v"(A0), "+v"(B0));
      asm volatile("v_permlane32_swap_b32 %0, %1" : "+v"(A1), "+v"(B1));
      int4v t = {(int)A0, (int)A1, (int)B0, (int)B1};
      pf[ks] = __builtin_bit_cast(bf16x8, t);
    }

    // PV: O^T += V^T.P^T (2 d-tiles x 2 k-steps)
    __builtin_amdgcn_s_setprio(1);
#pragma unroll
    for (int dt = 0; dt < 2; ++dt) {
      int dv = dt * 32 + lq;
#pragma unroll
      for (int ks = 0; ks < 2; ++ks) {
        const __bf16* vp = &Vb[dv * 32 + (((ks * 2 + hh) ^ ((dv >> 1) & 3)) * 8)];
        if (dt == 0)
          acc0 = mfma32(*(const bf16x8*)vp, pf[ks], acc0);
        else
          acc1 = mfma32(*(const bf16x8*)vp, pf[ks], acc1);
      }
    }
    __builtin_amdgcn_s_setprio(0);
  };

  // prologue: stage tiles 0,1
  stage(0, 0);
  stage(1, 1);
  __builtin_amdgcn_sched_barrier(0);
  asm volatile("s_waitcnt vmcnt(0)" ::: "memory");
  __builtin_amdgcn_s_barrier();
  asm volatile("" ::: "memory");
  __builtin_amdgcn_sched_barrier(0);

  for (int win = 0; win < 16; ++win) {
    const int p = (win & 1) * 2;
    if (win < 15) {
      stage(p ^ 2, 2 * win + 2);
      stage((p ^ 2) + 1, 2 * win + 3);
    }
    processTile(2 * win, &Ks[p][0], &Vs[p][0]);
    processTile(2 * win + 1, &Ks[p + 1][0], &Vs[p + 1][0]);
    __builtin_amdgcn_sched_barrier(0);
    asm volatile("s_waitcnt vmcnt(0)" ::: "memory");
    __builtin_amdgcn_s_barrier();
    asm volatile("" ::: "memory");
    __builtin_amdgcn_sched_barrier(0);
  }

  // normalize + write ctx: d = 32dt + 8rg + 4hh + ri
  float inv = 1.0f / l_run;
  __bf16* cp = ctx + ((size_t)(b * 1024 + qrow)) * 512 + h * 64 + hh * 4;
#pragma unroll
  for (int dt = 0; dt < 2; ++dt) {
#pragma unroll
    for (int rg = 0; rg < 4; ++rg) {
      bf16x4 ov;
#pragma unroll
      for (int ri = 0; ri < 4; ++ri)
        ov[ri] = (__bf16)((dt == 0 ? acc0[rg * 4 + ri] : acc1[rg * 4 + ri]) * inv);
      *(bf16x4*)(cp + dt * 32 + rg * 8) = ov;
    }
  }
}

extern "C" void kernel_launch(void* const* d_in, const int* in_sizes, int n_in,
                              void* d_out, int out_size, void* d_ws, size_t ws_size,
                              hipStream_t stream) {
  (void)in_sizes; (void)n_in; (void)out_size; (void)ws_size;
  const float* x     = (const float*)d_in[0];
  const float* U     = (const float*)d_in[1];
  const float* mask  = (const float*)d_in[2];
  const float* w_qkv = (const float*)d_in[3];
  const float* b_qkv = (const float*)d_in[4];
  const float* w_out = (const float*)d_in[5];
  const float* b_out = (const float*)d_in[6];
  float* out = (float*)d_out;

  char* p = (char*)d_ws;
  __bf16* xb    = (__bf16*)p; p += (size_t)8192 * 512 * 2;
  __bf16* wqkvT = (__bf16*)p; p += (size_t)1536 * 512 * 2;
  __bf16* woutT = (__bf16*)p; p += (size_t)512 * 512 * 2;
  __bf16* Qh    = (__bf16*)p; p += (size_t)64 * 1024 * 64 * 2;
  __bf16* Kh    = (__bf16*)p; p += (size_t)64 * 1024 * 64 * 2;
  __bf16* Vth   = (__bf16*)p; p += (size_t)64 * 64 * 1024 * 2;
  __bf16* ctx   = (__bf16*)p; p += (size_t)8192 * 512 * 2;

  hipLaunchKernelGGL(cast_x_kernel, dim3(2048), dim3(256), 0, stream,
                     x, xb, 8192 * 512 / 4);
  hipLaunchKernelGGL(transpose_both_kernel, dim3(64, 16), dim3(32, 8), 0, stream,
                     w_qkv, w_out, wqkvT, woutT);
  hipLaunchKernelGGL(gemm_qkv_kernel, dim3(64, 12), dim3(256), 0, stream,
                     xb, wqkvT, b_qkv, Qh, Kh, Vth);
  hipLaunchKernelGGL(attn_kernel, dim3(64, 16), dim3(128), 0, stream,
                     Qh, Kh, Vth, U, mask, ctx);
  hipLaunchKernelGGL(gemm_out_kernel, dim3(128, 8), dim3(256), 0, stream,
                     ctx, woutT, b_out, out);
}